// Round 1
// baseline (1468.278 us; speedup 1.0000x reference)
//
#include <hip/hip_runtime.h>
#include <stdint.h>

#define E_EDGES 200000
#define D_FEAT  256
#define K1      1024     // 4*D
#define HID     512
#define DOUT    256
#define M_TILE  64
#define BK      64
#define NCHUNK  256

#define SA_PITCH 72      // halfwords: 64 + 8 pad (balanced banks for b128 r/w)

typedef short bf16x8 __attribute__((ext_vector_type(8)));
typedef float f32x4  __attribute__((ext_vector_type(4)));

static_assert(E_EDGES % M_TILE == 0, "exact tiling, no tail");

#define GLOAD16(gp, lp) __builtin_amdgcn_global_load_lds( \
    (const __attribute__((address_space(1))) void*)(gp),  \
    (__attribute__((address_space(3))) void*)(lp), 16, 0, 0)

__device__ __forceinline__ unsigned short f2bf(float x) {
    unsigned int u = __builtin_bit_cast(unsigned int, x);
    u += 0x7FFFu + ((u >> 16) & 1u);           // RNE
    return (unsigned short)(u >> 16);
}

// ---- prep: W1 [1024,512] -> w1t bf16 [512,1024]; W2 [512,256] -> w2t bf16 [256,512]
__global__ void prep_weights(const float* __restrict__ W1, const float* __restrict__ W2,
                             unsigned short* __restrict__ w1t, unsigned short* __restrict__ w2t) {
    int idx = blockIdx.x * 256 + threadIdx.x;
    if (idx < HID * K1) {
        int n = idx >> 10;          // 0..511  (HID)
        int k = idx & 1023;         // 0..1023 (K1)
        w1t[idx] = f2bf(W1[k * HID + n]);
    } else if (idx < HID * K1 + DOUT * HID) {
        int j = idx - HID * K1;
        int n = j >> 9;             // 0..255 (DOUT)
        int k = j & 511;            // 0..511 (HID)
        w2t[j] = f2bf(W2[k * DOUT + n]);
    }
}

__launch_bounds__(256, 3)
__global__ void edge_mlp_kernel(const float* __restrict__ src,
                                const float* __restrict__ dst,
                                const float* __restrict__ ea,
                                const float* __restrict__ u,
                                const int*   __restrict__ batch,
                                const float* __restrict__ b1,
                                const float* __restrict__ b2,
                                const unsigned short* __restrict__ w1t,
                                const unsigned short* __restrict__ w2t,
                                float* __restrict__ out) {
    __shared__ unsigned short sA[M_TILE * SA_PITCH];   // 9216 B  (X tile / fused-H tile)
    __shared__ unsigned short sB[NCHUNK * BK];         // 32768 B (weights, XOR-swizzled)
    __shared__ int sBatch[M_TILE];

    const int tid  = threadIdx.x;
    const int lane = tid & 63;
    const int wave = tid >> 6;                 // 0..3
    const int cw   = wave << 6;                // col group 0/64/128/192 (both layers)
    const int lrow = lane & 15;
    const int quad = lane >> 4;
    const int e0   = blockIdx.x * M_TILE;

    if (tid < M_TILE) sBatch[tid] = batch[e0 + tid];

    // X staging coords (loop-invariant): thread -> (row, 16-float column chunk)
    const int ar  = tid >> 2;                  // 0..63
    const int acq = (tid & 3) << 4;            // 0/16/32/48

    const f32x4 z4 = {0.f, 0.f, 0.f, 0.f};
    f32x4 oacc[4][4];
#pragma unroll
    for (int i = 0; i < 4; ++i)
#pragma unroll
        for (int j = 0; j < 4; ++j) oacc[i][j] = z4;

    for (int c = 0; c < 2; ++c) {
        const int nb = c * NCHUNK;             // H-column base of this chunk
        f32x4 hacc[4][4];
#pragma unroll
        for (int i = 0; i < 4; ++i)
#pragma unroll
            for (int j = 0; j < 4; ++j) hacc[i][j] = z4;

        // ---- layer-1 K loop ----
        for (int k0 = 0; k0 < K1; k0 += BK) {
            __syncthreads();
            // stage W1^T tile [256 x 64] bf16 via global_load_lds.
            // LDS dest linear; global source pre-swizzled: b_log = b_lin ^ ((row&7)<<4)
#pragma unroll
            for (int i = 0; i < 8; ++i) {
                const int ob   = ((wave << 3) + i) << 10;     // wave-uniform LDS byte base
                const int o    = ob + (lane << 4);            // this lane's linear byte
                const int row  = o >> 7;                      // [256][128B] row
                const int blog = (o & 127) ^ ((row & 7) << 4);
                const char* g = (const char*)(w1t + (size_t)(nb + row) * K1 + k0) + blog;
                GLOAD16(g, (char*)sB + ob);
            }
            // stage X tile [64 x 64] (gathered, fp32 -> bf16), reg-staged
            {
                const int seg = k0 >> 8;
                const int ko  = (k0 & 255) + acq;
                const float* base;
                if      (seg == 0) base = src + (size_t)(e0 + ar) * D_FEAT;
                else if (seg == 1) base = dst + (size_t)(e0 + ar) * D_FEAT;
                else if (seg == 2) base = ea  + (size_t)(e0 + ar) * D_FEAT;
                else               base = u   + (size_t)sBatch[ar] * D_FEAT;
                const float4* p = reinterpret_cast<const float4*>(base + ko);
                float4 f0 = p[0], f1 = p[1], f2v = p[2], f3 = p[3];
                unsigned int w0 = (unsigned)f2bf(f0.x)  | ((unsigned)f2bf(f0.y)  << 16);
                unsigned int w1 = (unsigned)f2bf(f0.z)  | ((unsigned)f2bf(f0.w)  << 16);
                unsigned int w2 = (unsigned)f2bf(f1.x)  | ((unsigned)f2bf(f1.y)  << 16);
                unsigned int w3 = (unsigned)f2bf(f1.z)  | ((unsigned)f2bf(f1.w)  << 16);
                unsigned int w4 = (unsigned)f2bf(f2v.x) | ((unsigned)f2bf(f2v.y) << 16);
                unsigned int w5 = (unsigned)f2bf(f2v.z) | ((unsigned)f2bf(f2v.w) << 16);
                unsigned int w6 = (unsigned)f2bf(f3.x)  | ((unsigned)f2bf(f3.y)  << 16);
                unsigned int w7 = (unsigned)f2bf(f3.z)  | ((unsigned)f2bf(f3.w)  << 16);
                uint4* dsp = reinterpret_cast<uint4*>(&sA[ar * SA_PITCH + acq]);
                dsp[0] = make_uint4(w0, w1, w2, w3);
                dsp[1] = make_uint4(w4, w5, w6, w7);
            }
            __syncthreads();
#pragma unroll
            for (int kk = 0; kk < BK; kk += 32) {
                bf16x8 af[4], bfr[4];
#pragma unroll
                for (int i = 0; i < 4; ++i)
                    af[i] = *reinterpret_cast<const bf16x8*>(&sA[(i * 16 + lrow) * SA_PITCH + kk + quad * 8]);
#pragma unroll
                for (int j = 0; j < 4; ++j) {
                    const int row = cw + j * 16 + lrow;
                    const int k2  = (kk + quad * 8) ^ ((row & 7) << 3);   // halfword-index swizzle
                    bfr[j] = *reinterpret_cast<const bf16x8*>(&sB[(row << 6) + k2]);
                }
#pragma unroll
                for (int i = 0; i < 4; ++i)
#pragma unroll
                    for (int j = 0; j < 4; ++j)
                        hacc[i][j] = __builtin_amdgcn_mfma_f32_16x16x32_bf16(af[i], bfr[j], hacc[i][j], 0, 0, 0);
            }
        }

        // ---- fused layer-2: 4 sub-steps of 64 H-cols, H round-trips through sA ----
        for (int k20 = 0; k20 < NCHUNK; k20 += BK) {
            __syncthreads();
            // stage W2 tile [256 x 64] bf16 (same swizzle scheme)
#pragma unroll
            for (int i = 0; i < 8; ++i) {
                const int ob   = ((wave << 3) + i) << 10;
                const int o    = ob + (lane << 4);
                const int row  = o >> 7;
                const int blog = (o & 127) ^ ((row & 7) << 4);
                const char* g = (const char*)(w2t + (size_t)row * HID + nb + k20) + blog;
                GLOAD16(g, (char*)sB + ob);
            }
            // owner wave materializes its H columns: bias + relu -> bf16 into sA
            if (cw == k20) {
#pragma unroll
                for (int j = 0; j < 4; ++j) {
                    const int col = (j << 4) + lrow;
                    const float bb = b1[nb + k20 + col];
#pragma unroll
                    for (int i = 0; i < 4; ++i) {
#pragma unroll
                        for (int r = 0; r < 4; ++r) {
                            const int row = (i << 4) + (quad << 2) + r;
                            float v = hacc[i][j][r] + bb;
                            v = fmaxf(v, 0.f);
                            sA[row * SA_PITCH + col] = f2bf(v);
                        }
                    }
                }
            }
            __syncthreads();
#pragma unroll
            for (int kk = 0; kk < BK; kk += 32) {
                bf16x8 af[4], bfr[4];
#pragma unroll
                for (int i = 0; i < 4; ++i)
                    af[i] = *reinterpret_cast<const bf16x8*>(&sA[(i * 16 + lrow) * SA_PITCH + kk + quad * 8]);
#pragma unroll
                for (int j = 0; j < 4; ++j) {
                    const int row = cw + j * 16 + lrow;            // output col 0..255
                    const int k2  = (kk + quad * 8) ^ ((row & 7) << 3);
                    bfr[j] = *reinterpret_cast<const bf16x8*>(&sB[(row << 6) + k2]);
                }
#pragma unroll
                for (int i = 0; i < 4; ++i)
#pragma unroll
                    for (int j = 0; j < 4; ++j)
                        oacc[i][j] = __builtin_amdgcn_mfma_f32_16x16x32_bf16(af[i], bfr[j], oacc[i][j], 0, 0, 0);
            }
        }
    }

    // ---- final epilogue: + b2, store fp32 (E % 64 == 0, no clamp) ----
#pragma unroll
    for (int j = 0; j < 4; ++j) {
        const int col = cw + (j << 4) + lrow;
        const float bb = b2[col];
#pragma unroll
        for (int i = 0; i < 4; ++i) {
            const int rbase = (i << 4) + (quad << 2);
#pragma unroll
            for (int r = 0; r < 4; ++r) {
                const int row = rbase + r;
                out[(size_t)(e0 + row) * DOUT + col] = oacc[i][j][r] + bb;
            }
        }
    }
}

extern "C" void kernel_launch(void* const* d_in, const int* in_sizes, int n_in,
                              void* d_out, int out_size, void* d_ws, size_t ws_size,
                              hipStream_t stream) {
    (void)in_sizes; (void)n_in; (void)out_size; (void)ws_size;
    const float* src  = (const float*)d_in[0];
    const float* dst  = (const float*)d_in[1];
    const float* ea   = (const float*)d_in[2];
    const float* u    = (const float*)d_in[3];
    const int*   bat  = (const int*)d_in[4];
    const float* W1   = (const float*)d_in[5];
    const float* b1   = (const float*)d_in[6];
    const float* W2   = (const float*)d_in[7];
    const float* b2   = (const float*)d_in[8];
    float* out = (float*)d_out;

    unsigned short* w1t = (unsigned short*)d_ws;             // 512*1024 bf16 = 1 MiB
    unsigned short* w2t = w1t + (size_t)HID * K1;            // 256*512  bf16 = 256 KiB

    prep_weights<<<(HID * K1 + DOUT * HID) / 256, 256, 0, stream>>>(W1, W2, w1t, w2t);

    const int nblocks = E_EDGES / M_TILE;                    // 3125
    edge_mlp_kernel<<<nblocks, 256, 0, stream>>>(src, dst, ea, u, bat, b1, b2, w1t, w2t, out);
}